// Round 4
// baseline (595.911 us; speedup 1.0000x reference)
//
#include <hip/hip_runtime.h>

#define NROWS    262144   // 16 * 16384
#define DIMS     64
#define KCODES   512
#define MTILE    64       // rows per block (8 waves x 8 rows)
#define RPW      8        // rows per wave
#define CHUNK    256      // epilogue col-half width (col->lane ownership, frozen)
#define NCHUNK   2        // col halves per lane (8 cols/lane total, frozen)
#define D_PER    16       // dims per LDS stage  -> 16*512*4 = 32 KB
#define D_CHUNKS 4        // 64 / 16
#define NTHREADS 512

// ---------------------------------------------------------------------------
// prep: embedT[k][d] = embed[d][k]; enorm[k] = sum_d embed[d][k]^2 (numpy
// pairwise-8 order); zero the likelihood accumulator.
// grid <<<512, 64>>> : block = one code k, lane = d.
// ---------------------------------------------------------------------------
__global__ void prep_kernel(const float* __restrict__ embed,
                            float* __restrict__ embedT,
                            float* __restrict__ enorm,
                            float* __restrict__ lik) {
    int k = blockIdx.x;
    int d = threadIdx.x;
    float v = embed[d * KCODES + k];
    embedT[k * DIMS + d] = v;
    float sq = __fmul_rn(v, v);
    // numpy pairwise: r_j = sq_j + sq_{j+8} + ... (sequential), j = d & 7
    int j = d & 7;
    float r = __shfl(sq, j, 64);
#pragma unroll
    for (int i = 1; i < 8; ++i)
        r = __fadd_rn(r, __shfl(sq, j + 8 * i, 64));
    // combine ((r0+r1)+(r2+r3)) + ((r4+r5)+(r6+r7)) via xor tree (bitwise exact)
    float t;
    t = __shfl_xor(r, 1, 64); r = __fadd_rn(r, t);
    t = __shfl_xor(r, 2, 64); r = __fadd_rn(r, t);
    t = __shfl_xor(r, 4, 64); r = __fadd_rn(r, t);
    if (d == 0) { enorm[k] = r; lik[k] = 0.0f; }
}

// ---------------------------------------------------------------------------
// main: fused GEMM + softmax + argmax + hard-gather + likelihood partials.
// grid <<<4096, 512>>>. Block: 64 rows x 512 cols.
// Thread (cg = tid&63, rg = tid>>6): 8 rows x 8 cols -> acc[2][8][4] = 64
// VGPRs. Wave = one rg = 8 full rows (in-wave softmax).
//
// ROUND-4: rows/wave back to 8 (from 4) to halve DS-pipe traffic per fma —
// round-3 counters showed the per-CU DS unit is the heaviest pipe (~214 us of
// ds_read/swizzle occupancy vs ~109 us VALU fma) while nothing saturated
// (VALU 52%, DS ~40%). Each LDS e-float4 now feeds 8 rows instead of 4.
// The round-0 RPW=8 spill (VGPR pinned 64, 288 MiB scratch writebacks) was
// caused by __launch_bounds__(512,4) acting as min-BLOCKS/CU (32 waves/CU ->
// 64-reg cap). __launch_bounds__(512,2) caps at >=128 regs under either
// semantics (2 blocks/CU -> 16 waves -> 128; or 2 waves/EU -> 256), so the
// ~110-reg live set (acc 64 + 2x16 e + x + addr) fits without spill.
// LDS stays 32 KB (d-chunked staging, 4 stages of e[16][512]).
// ---------------------------------------------------------------------------
__launch_bounds__(NTHREADS, 2)
__global__ void main_kernel(const float* __restrict__ x,
                            const float* __restrict__ embed,
                            const float* __restrict__ sigma,
                            const float* __restrict__ embedT,
                            const float* __restrict__ enorm,
                            float* __restrict__ lik,
                            float* __restrict__ out) {
    __shared__ float e_lds[D_PER * KCODES];   // 32 KB

    const int tid = threadIdx.x;
    const int cg  = tid & 63;        // col group (4 cols per half)
    const int rg  = tid >> 6;        // row group (8 rows), == wave id
    const int rowbase = blockIdx.x * MTILE + rg * RPW;

    const float sigma_v = sigma[0];

    float acc[NCHUNK][RPW][4];
#pragma unroll
    for (int c = 0; c < NCHUNK; ++c)
#pragma unroll
        for (int r = 0; r < RPW; ++r)
#pragma unroll
            for (int q = 0; q < 4; ++q) acc[c][r][q] = 0.0f;

    const float2* __restrict__ x2  = reinterpret_cast<const float2*>(x);
    const float4* __restrict__ eg4 = reinterpret_cast<const float4*>(embed);
    float4* e_lds4 = reinterpret_cast<float4*>(e_lds);

    for (int dc = 0; dc < D_CHUNKS; ++dc) {
        __syncthreads();   // protect previous stage's readers
        // stage e[dc*16 .. dc*16+15][0..511]: perfectly linear float4 copy
#pragma unroll
        for (int i = 0; i < 4; ++i) {
            int f4 = tid + i * NTHREADS;          // 0..2047
            e_lds4[f4] = eg4[dc * (D_PER * KCODES / 4) + f4];
        }
        __syncthreads();

        const float4* e4 = reinterpret_cast<const float4*>(e_lds);
#pragma unroll 2
        for (int d2 = 0; d2 < D_PER / 2; ++d2) {     // dim pairs within stage
            // e rows for dims (2*d2, 2*d2+1), both col halves (4 cols each)
            float4 e0a = e4[(2 * d2 + 0) * 128 +  0 + cg];   // dim lo, half 0
            float4 e1a = e4[(2 * d2 + 1) * 128 +  0 + cg];   // dim hi, half 0
            float4 e0b = e4[(2 * d2 + 0) * 128 + 64 + cg];   // dim lo, half 1
            float4 e1b = e4[(2 * d2 + 1) * 128 + 64 + cg];   // dim hi, half 1
            int d2g = dc * (D_PER / 2) + d2;                 // global dim-pair
#pragma unroll
            for (int r = 0; r < RPW; ++r) {
                float2 xv = x2[(size_t)(rowbase + r) * 32 + d2g];
                // ascending-d sequential fma chain per (r,col) — bit-exact
                acc[0][r][0] = fmaf(xv.x, e0a.x, acc[0][r][0]);
                acc[0][r][1] = fmaf(xv.x, e0a.y, acc[0][r][1]);
                acc[0][r][2] = fmaf(xv.x, e0a.z, acc[0][r][2]);
                acc[0][r][3] = fmaf(xv.x, e0a.w, acc[0][r][3]);
                acc[0][r][0] = fmaf(xv.y, e1a.x, acc[0][r][0]);
                acc[0][r][1] = fmaf(xv.y, e1a.y, acc[0][r][1]);
                acc[0][r][2] = fmaf(xv.y, e1a.z, acc[0][r][2]);
                acc[0][r][3] = fmaf(xv.y, e1a.w, acc[0][r][3]);
                acc[1][r][0] = fmaf(xv.x, e0b.x, acc[1][r][0]);
                acc[1][r][1] = fmaf(xv.x, e0b.y, acc[1][r][1]);
                acc[1][r][2] = fmaf(xv.x, e0b.z, acc[1][r][2]);
                acc[1][r][3] = fmaf(xv.x, e0b.w, acc[1][r][3]);
                acc[1][r][0] = fmaf(xv.y, e1b.x, acc[1][r][0]);
                acc[1][r][1] = fmaf(xv.y, e1b.y, acc[1][r][1]);
                acc[1][r][2] = fmaf(xv.y, e1b.z, acc[1][r][2]);
                acc[1][r][3] = fmaf(xv.y, e1b.w, acc[1][r][3]);
            }
        }
    }

    // ---- xnorm for the wave's 8 rows, numpy pairwise-8 order ----
    // lane cg = r_l*8 + j_l computes partial r_{j_l} of row r_l
    const int r_l = cg >> 3;
    const int j_l = cg & 7;
    float xr;
    {
        const float* xp = x + (size_t)(rowbase + r_l) * DIMS + j_l;
        float v0 = xp[0];
        float s = __fmul_rn(v0, v0);
#pragma unroll
        for (int i = 1; i < 8; ++i) {
            float v = xp[8 * i];
            s = __fadd_rn(s, __fmul_rn(v, v));
        }
        xr = s;
    }
    {
        float t;
        t = __shfl_xor(xr, 1, 64); xr = __fadd_rn(xr, t);
        t = __shfl_xor(xr, 2, 64); xr = __fadd_rn(xr, t);
        t = __shfl_xor(xr, 4, 64); xr = __fadd_rn(xr, t);
    }
    // lane r*8+j now holds xnorm of row r (r = 0..7)

    // enorm for this thread's 8 cols
    float en[NCHUNK][4];
#pragma unroll
    for (int c = 0; c < NCHUNK; ++c)
#pragma unroll
        for (int q = 0; q < 4; ++q)
            en[c][q] = enorm[c * CHUNK + cg * 4 + q];

    float likpart[NCHUNK][4];
#pragma unroll
    for (int c = 0; c < NCHUNK; ++c)
#pragma unroll
        for (int q = 0; q < 4; ++q) likpart[c][q] = 0.0f;

#pragma unroll
    for (int r = 0; r < RPW; ++r) {
        float xn = __shfl(xr, r * 8, 64);
        // z = -sigma * ((xnorm - 2*dot) + enorm), np-assembly order.
        // IN-PLACE: z overwrites acc[c][r][q] (dot is dead afterwards).
        float m = -INFINITY;
#pragma unroll
        for (int c = 0; c < NCHUNK; ++c)
#pragma unroll
            for (int q = 0; q < 4; ++q) {
                float dot  = acc[c][r][q];
                float td   = __fsub_rn(xn, __fmul_rn(2.0f, dot));
                float dist = __fadd_rn(td, en[c][q]);
                float zz   = __fmul_rn(-sigma_v, dist);
                acc[c][r][q] = zz;
                m = fmaxf(m, zz);
            }
#pragma unroll
        for (int mask = 1; mask < 64; mask <<= 1)
            m = fmaxf(m, __shfl_xor(m, mask, 64));

        // ev overwrites z in place
        float s = 0.0f;
        float bv = -1.0f;
        int   bc = KCODES;
#pragma unroll
        for (int c = 0; c < NCHUNK; ++c)
#pragma unroll
            for (int q = 0; q < 4; ++q) {
                float ee = expf(__fsub_rn(acc[c][r][q], m));
                acc[c][r][q] = ee;
                s += ee;
                int col = c * CHUNK + cg * 4 + q;
                if (ee > bv) { bv = ee; bc = col; }   // first-index tiebreak
            }
#pragma unroll
        for (int mask = 1; mask < 64; mask <<= 1)
            s += __shfl_xor(s, mask, 64);
#pragma unroll
        for (int mask = 1; mask < 64; mask <<= 1) {
            float ov = __shfl_xor(bv, mask, 64);
            int   oc = __shfl_xor(bc, mask, 64);
            if (ov > bv || (ov == bv && oc < bc)) { bv = ov; bc = oc; }
        }

        float invS = 1.0f / s;
#pragma unroll
        for (int c = 0; c < NCHUNK; ++c)
#pragma unroll
            for (int q = 0; q < 4; ++q)
                likpart[c][q] = fmaf(acc[c][r][q], invS, likpart[c][q]);

        // hard-gather write: quantize[row][cg] = embedT[bc][cg]
        // nontemporal: avoid write-allocate RFO on the 64 MB output
        int row = rowbase + r;
        __builtin_nontemporal_store(embedT[bc * DIMS + cg],
                                    &out[(size_t)row * DIMS + cg]);
    }

    // ---- block-level likelihood reduction (reuse e_lds) ----
    float* red = e_lds;
    __syncthreads();
    red[tid] = 0.0f;
    __syncthreads();
#pragma unroll
    for (int c = 0; c < NCHUNK; ++c)
#pragma unroll
        for (int q = 0; q < 4; ++q)
            atomicAdd(&red[c * CHUNK + cg * 4 + q], likpart[c][q]);
    __syncthreads();
    atomicAdd(&lik[tid], red[tid]);
}

// ---------------------------------------------------------------------------
// finish: likelihoods = lik_sum / N; quant_loss = 0.25 * mean(p*(log p - log(l+eps)))
// ---------------------------------------------------------------------------
__global__ void finish_kernel(const float* __restrict__ lik,
                              float* __restrict__ out) {
    int tid = threadIdx.x;   // 512 threads
    float l = lik[tid] / 262144.0f;     // exact: divide by 2^18
    out[16777217 + tid] = l;
    const float p = 1.0f / 512.0f;
    float term = __fmul_rn(p, __fsub_rn(logf(p), logf(l + 1e-10f)));
#pragma unroll
    for (int mask = 1; mask < 64; mask <<= 1)
        term += __shfl_xor(term, mask, 64);
    __shared__ float ws[8];
    if ((tid & 63) == 0) ws[tid >> 6] = term;
    __syncthreads();
    if (tid == 0) {
        float ssum = 0.0f;
        for (int i = 0; i < 8; ++i) ssum += ws[i];
        out[16777216] = 0.25f * (ssum / 512.0f);
    }
}

extern "C" void kernel_launch(void* const* d_in, const int* in_sizes, int n_in,
                              void* d_out, int out_size, void* d_ws, size_t ws_size,
                              hipStream_t stream) {
    const float* x     = (const float*)d_in[0];
    const float* embed = (const float*)d_in[1];
    const float* sigma = (const float*)d_in[2];
    float* out = (float*)d_out;
    float* ws  = (float*)d_ws;

    float* embedT = ws;             // 512*64 = 32768 floats
    float* enorm  = ws + 32768;     // 512 floats
    float* lik    = ws + 33280;     // 512 floats

    prep_kernel<<<KCODES, DIMS, 0, stream>>>(embed, embedT, enorm, lik);
    main_kernel<<<NROWS / MTILE, NTHREADS, 0, stream>>>(x, embed, sigma,
                                                        embedT, enorm, lik, out);
    finish_kernel<<<1, NTHREADS, 0, stream>>>(lik, out);
}